// Round 5
// baseline (243.477 us; speedup 1.0000x reference)
//
#include <hip/hip_runtime.h>
#include <hip/hip_bf16.h>

#define TOKENS (16*1024)
#define HD 512
#define MM 2048
#define TB 16   // tokens per stage_a block

typedef short s16x8 __attribute__((ext_vector_type(8)));
typedef float f32x4 __attribute__((ext_vector_type(4)));

__device__ __forceinline__ __hip_bfloat16 f2bf(float v){ return __float2bfloat16(v); }
__device__ __forceinline__ float bf2f(__hip_bfloat16 v){ return __bfloat162float(v); }
__device__ __forceinline__ unsigned short f2bfu(float v){
  __hip_bfloat16 b = __float2bfloat16(v);
  unsigned short u; __builtin_memcpy(&u, &b, 2); return u;
}
__device__ __forceinline__ float bfu2f(unsigned short u){
  unsigned int x = ((unsigned int)u) << 16; float f; __builtin_memcpy(&f, &x, 4); return f;
}
__device__ __forceinline__ uint4 pack8(const float* v){
  unsigned short s[8];
  #pragma unroll
  for (int e = 0; e < 8; e++) s[e] = f2bfu(v[e]);
  uint4 u; __builtin_memcpy(&u, s, 16); return u;
}
__device__ __forceinline__ void unpack8(uint4 u, float* v){
  const unsigned short* s = (const unsigned short*)&u;
  #pragma unroll
  for (int e = 0; e < 8; e++) v[e] = bfu2f(s[e]);
}

// async global->LDS, 16B per lane
typedef const __attribute__((address_space(1))) unsigned int* gas_t;
typedef __attribute__((address_space(3))) unsigned int* las_t;
__device__ __forceinline__ void async16(const void* g, void* l){
  __builtin_amdgcn_global_load_lds((gas_t)g, (las_t)l, 16, 0, 0);
}

#define SWZ(t) (((t) & 7) << 4)                     // Xa byte-address swizzle
#define TSW(t) (((((t) & 3) ^ ((t) >> 2))) << 4)    // P/R element-index swizzle

// ---- MFMA projection; Wt: bf16 pre-transposed [c][d][64k], contiguous k ----
// MODE 0: P[t][outOff + c*ND + d] (swizzled)   MODE 1: R += (swizzled)
// MODE 2: xca global f32 + R (swizzled)
template<int ND, int MODE>
__device__ __forceinline__ void proj_mfma(
    const unsigned char* Xa, unsigned short* P, unsigned short* R,
    const __hip_bfloat16* __restrict__ Wt, int wCs,
    const float* __restrict__ bias, int bCs,
    int outOff, float* __restrict__ xca, size_t tokbase,
    int wave, int lane)
{
  const int lr = lane & 15, lg = lane >> 4, lk = lg * 8;
  constexpr int NT = ND / 16, TOT = 8 * NT;
  #pragma unroll 2
  for (int tile = wave; tile < TOT; tile += 4){
    int c = tile / NT, nt = tile - c * NT;
    f32x4 acc = {0.f, 0.f, 0.f, 0.f};
    #pragma unroll
    for (int ks = 0; ks < 2; ks++){
      int k0 = ks * 32 + lk;
      int aaddr = (((c * 16 + lr) * 64 + k0) * 2) ^ SWZ(lr);
      s16x8 af = *(const s16x8*)(Xa + aaddr);
      s16x8 bfr = *(const s16x8*)((const void*)(Wt + (size_t)c * wCs + (nt*16 + lr) * 64 + k0));
      acc = __builtin_amdgcn_mfma_f32_16x16x32_bf16(af, bfr, acc, 0, 0, 0);
    }
    float bsv = bias[c * bCs + nt * 16 + lr];
    int dcol = c * ND + nt * 16 + lr;
    #pragma unroll
    for (int r = 0; r < 4; r++){
      int t = lg * 4 + r;
      float val = acc[r] + bsv;
      if (MODE == 0){
        P[(t * 1536 + outOff + dcol) ^ TSW(t)] = f2bfu(val);
      } else if (MODE == 1){
        unsigned short* rp = &R[(t * 512 + dcol) ^ TSW(t)];
        *rp = f2bfu(bfu2f(*rp) + val);
      } else {
        xca[(tokbase + t) * HD + dcol] = val;
        R[(t * 512 + dcol) ^ TSW(t)] = f2bfu(val);
      }
    }
  }
}

// ---- criss-cross attention; e-row cached (exp once), swizzled P reads ----
template<int V>
__device__ __forceinline__ void cc_attn(const unsigned short* P, unsigned char* Xa, int tid)
{
  const int t = tid >> 4, j0 = tid & 15;
  const unsigned short* pr = P + t * 1536;
  const int xr = TSW(t);
  #pragma unroll
  for (int jj = 0; jj < 4; jj++){
    int j = j0 + jj * 16;
    int js = j ^ xr;              // all row offsets are multiples of 64 -> fold XOR into j
    float qs[8], kk[8], vv[8];
    #pragma unroll
    for (int m = 0; m < 8; m++){
      if (V == 1){
        qs[m] = bfu2f(pr[m * 192 + js]) * 0.125f;
        kk[m] = bfu2f(pr[m * 192 + 64 + js]);
        vv[m] = bfu2f(pr[m * 192 + 128 + js]);
      } else {
        qs[m] = bfu2f(pr[m * 64 + js]) * 0.125f;
        kk[m] = bfu2f(pr[512 + m * 128 + js]);
        vv[m] = bfu2f(pr[512 + m * 128 + 64 + js]);
      }
    }
    float out[8];
    #pragma unroll
    for (int m = 0; m < 8; m++) out[m] = 0.f;
    #pragma unroll
    for (int c = 0; c < 8; c++){
      float er[8]; float den = 0.f;
      #pragma unroll
      for (int m = 0; m < 8; m++){ er[m] = __expf(qs[c] * kk[m]); den += er[m]; }
      float wc = vv[c] / den;
      #pragma unroll
      for (int m = 0; m < 8; m++) out[m] += wc * er[m];
    }
    #pragma unroll
    for (int m = 0; m < 8; m++){
      int addr = (((m * 16 + t) * 64 + j) * 2) ^ SWZ(t);
      *(unsigned short*)(Xa + addr) = f2bfu(out[m]);
    }
  }
}

__global__ __launch_bounds__(256)
void fused_stage_a(const float* __restrict__ x, const float* __restrict__ ctx,
                   const float* __restrict__ ln1w, const float* __restrict__ ln1b,
                   const __hip_bfloat16* __restrict__ qkvT, const float* __restrict__ b_qkv,
                   const __hip_bfloat16* __restrict__ fcsT, const float* __restrict__ b_fcs,
                   const float* __restrict__ ln2w, const float* __restrict__ ln2b,
                   const __hip_bfloat16* __restrict__ qT, const float* __restrict__ b_q,
                   const __hip_bfloat16* __restrict__ kvT, const float* __restrict__ b_kv,
                   const __hip_bfloat16* __restrict__ fccT, const float* __restrict__ b_fcc,
                   const float* __restrict__ ln3w, const float* __restrict__ ln3b,
                   float* __restrict__ xca_out, __hip_bfloat16* __restrict__ y_out)
{
  __shared__ __align__(16) unsigned char lds[81920];
  unsigned char*  Xa = lds;                              // [8][16][64] bf16, swizzled (16 KB)
  unsigned short* P  = (unsigned short*)(lds + 16384);   // [16][1536] bf16, swizzled (48 KB)
  unsigned short* R  = (unsigned short*)(lds + 65536);   // [16][512]  bf16, swizzled (16 KB)

  const int tid = threadIdx.x, lane = tid & 63, wave = tid >> 6;
  const size_t tokbase = (size_t)blockIdx.x * TB;
  const int cXa = lane >> 3, k0Xa = (lane & 7) * 8;

  // ---------- phase 1: LN1(x) -> Xa + R ----------
  {
    float lw[8], lb[8];
    #pragma unroll
    for (int e = 0; e < 8; e++){ lw[e] = ln1w[lane*8+e]; lb[e] = ln1b[lane*8+e]; }
    for (int tt = 0; tt < 4; tt++){
      int t = wave * 4 + tt;
      const float* xr = x + (tokbase + t) * HD + lane * 8;
      float v[8];
      float4 a0 = *(const float4*)xr, a1 = *(const float4*)(xr + 4);
      v[0]=a0.x; v[1]=a0.y; v[2]=a0.z; v[3]=a0.w; v[4]=a1.x; v[5]=a1.y; v[6]=a1.z; v[7]=a1.w;
      float sm = 0.f, sq = 0.f;
      #pragma unroll
      for (int e = 0; e < 8; e++){ sm += v[e]; sq += v[e]*v[e]; }
      #pragma unroll
      for (int o = 32; o > 0; o >>= 1){ sm += __shfl_xor(sm, o); sq += __shfl_xor(sq, o); }
      float mu = sm * (1.f/512.f), rs = rsqrtf(sq * (1.f/512.f) - mu*mu + 1e-6f);
      float nv[8];
      #pragma unroll
      for (int e = 0; e < 8; e++) nv[e] = (v[e]-mu)*rs*lw[e] + lb[e];
      uint4 pk = pack8(nv);
      *(uint4*)(R + ((t*512 + lane*8) ^ TSW(t))) = pk;
      *(uint4*)(Xa + ((((cXa*16 + t)*64 + k0Xa)*2) ^ SWZ(t))) = pk;
    }
  }
  __syncthreads();

  // ---------- phase 2: qkv projection ----------
  proj_mfma<192,0>(Xa, P, R, qkvT, 192*64, b_qkv, 192, 0, nullptr, tokbase, wave, lane);
  __syncthreads();

  // ---------- phase 3: attention #1 -> Xa ----------
  cc_attn<1>(P, Xa, tid);
  __syncthreads();

  // ---------- phase 4: fc_s, residual into R ----------
  proj_mfma<64,1>(Xa, P, R, fcsT, 0, b_fcs, 0, 0, nullptr, tokbase, wave, lane);
  __syncthreads();

  // ---------- phase 5: LN2(R) -> Xa (h) ----------
  {
    float lw[8], lb[8];
    #pragma unroll
    for (int e = 0; e < 8; e++){ lw[e] = ln2w[lane*8+e]; lb[e] = ln2b[lane*8+e]; }
    for (int tt = 0; tt < 4; tt++){
      int t = wave * 4 + tt;
      float v[8];
      unpack8(*(const uint4*)(R + ((t*512 + lane*8) ^ TSW(t))), v);
      float sm = 0.f, sq = 0.f;
      #pragma unroll
      for (int e = 0; e < 8; e++){ sm += v[e]; sq += v[e]*v[e]; }
      #pragma unroll
      for (int o = 32; o > 0; o >>= 1){ sm += __shfl_xor(sm, o); sq += __shfl_xor(sq, o); }
      float mu = sm * (1.f/512.f), rs = rsqrtf(sq * (1.f/512.f) - mu*mu + 1e-6f);
      float nv[8];
      #pragma unroll
      for (int e = 0; e < 8; e++) nv[e] = (v[e]-mu)*rs*lw[e] + lb[e];
      *(uint4*)(Xa + ((((cXa*16 + t)*64 + k0Xa)*2) ^ SWZ(t))) = pack8(nv);
    }
  }
  __syncthreads();

  // ---------- hoist ctx loads (hide HBM/L2 latency under q-proj) ----------
  float cvv[4][8];
  #pragma unroll
  for (int tt = 0; tt < 4; tt++){
    int t = wave * 4 + tt;
    const float* cr = ctx + (tokbase + t) * HD + lane * 8;
    float4 a0 = *(const float4*)cr, a1 = *(const float4*)(cr + 4);
    cvv[tt][0]=a0.x; cvv[tt][1]=a0.y; cvv[tt][2]=a0.z; cvv[tt][3]=a0.w;
    cvv[tt][4]=a1.x; cvv[tt][5]=a1.y; cvv[tt][6]=a1.z; cvv[tt][7]=a1.w;
  }

  // ---------- phase 6: q projection -> P[t][0:512] ----------
  proj_mfma<64,0>(Xa, P, R, qT, 64*64, b_q, 64, 0, nullptr, tokbase, wave, lane);
  __syncthreads();

  // ---------- phase 7: ctx regs -> Xa ----------
  #pragma unroll
  for (int tt = 0; tt < 4; tt++){
    int t = wave * 4 + tt;
    *(uint4*)(Xa + ((((cXa*16 + t)*64 + k0Xa)*2) ^ SWZ(t))) = pack8(cvv[tt]);
  }
  __syncthreads();

  // ---------- phase 8: kv projection -> P[t][512:1536] ----------
  proj_mfma<128,0>(Xa, P, R, kvT, 128*64, b_kv, 128, 512, nullptr, tokbase, wave, lane);
  __syncthreads();

  // ---------- phase 9: attention #2 -> Xa ----------
  cc_attn<2>(P, Xa, tid);
  __syncthreads();

  // ---------- phase 10: fc_c -> x_ca + R ----------
  proj_mfma<64,2>(Xa, P, R, fccT, 0, b_fcc, 0, 0, xca_out, tokbase, wave, lane);
  __syncthreads();

  // ---------- phase 11: LN3(R) -> y_out ----------
  {
    float lw[8], lb[8];
    #pragma unroll
    for (int e = 0; e < 8; e++){ lw[e] = ln3w[lane*8+e]; lb[e] = ln3b[lane*8+e]; }
    for (int tt = 0; tt < 4; tt++){
      int t = wave * 4 + tt;
      float v[8];
      unpack8(*(const uint4*)(R + ((t*512 + lane*8) ^ TSW(t))), v);
      float sm = 0.f, sq = 0.f;
      #pragma unroll
      for (int e = 0; e < 8; e++){ sm += v[e]; sq += v[e]*v[e]; }
      #pragma unroll
      for (int o = 32; o > 0; o >>= 1){ sm += __shfl_xor(sm, o); sq += __shfl_xor(sq, o); }
      float mu = sm * (1.f/512.f), rs = rsqrtf(sq * (1.f/512.f) - mu*mu + 1e-6f);
      float nv[8];
      #pragma unroll
      for (int e = 0; e < 8; e++) nv[e] = (v[e]-mu)*rs*lw[e] + lb[e];
      *(uint4*)(y_out + (tokbase + t) * HD + lane * 8) = pack8(nv);
    }
  }
}

// ===== batched tiled transpose+convert: src[c][K][D] f32 -> dst[c][D][K] bf16 =====
__global__ __launch_bounds__(256)
void convT(const float* __restrict__ src, __hip_bfloat16* __restrict__ dst, int K, int D)
{
  const int c = blockIdx.z;
  src += (size_t)c * K * D;
  dst += (size_t)c * D * K;
  __shared__ float tile[32][33];
  const int rb = blockIdx.x * 32, cb = blockIdx.y * 32;
  const int tr = threadIdx.x & 31, tg = threadIdx.x >> 5;
  #pragma unroll
  for (int i = 0; i < 4; i++){
    int r = tg * 4 + i;
    tile[r][tr] = src[(size_t)(rb + r) * D + cb + tr];
  }
  __syncthreads();
  #pragma unroll
  for (int i = 0; i < 4; i++){
    int rr = tg * 4 + i;
    dst[(size_t)(cb + rr) * K + rb + tr] = f2bf(tile[tr][rr]);
  }
}

// ===== MFMA GEMM (m97 structure, unchanged from round 4 — verified) =====
__device__ __forceinline__ float gelu_exact(float v){
  return 0.5f * v * (1.f + erff(v * 0.70710678118f));
}

template<int EPI>
__global__ __launch_bounds__(256)
void gemm_bt(const __hip_bfloat16* __restrict__ A, const __hip_bfloat16* __restrict__ Bt,
             const float* __restrict__ bias,
             __hip_bfloat16* __restrict__ DstB, float* __restrict__ DstF,
             int M_, int N_, int K_)
{
  __shared__ __align__(16) unsigned char lds[32768];
  unsigned char* As = lds;
  unsigned char* Bs = lds + 16384;

  const int tid = threadIdx.x, lane = tid & 63, wave = tid >> 6;
  const int row0 = blockIdx.x * 128, col0 = blockIdx.y * 128;
  const int lr = lane & 15, lg = lane >> 4;
  const int wr = (wave >> 1) * 64, wc = (wave & 1) * 64;
  const int srow = (lane >> 3), schunk = lane & 7;

  f32x4 acc[4][4];
  #pragma unroll
  for (int i = 0; i < 4; i++)
    #pragma unroll
    for (int j = 0; j < 4; j++)
      acc[i][j] = (f32x4){0.f, 0.f, 0.f, 0.f};

  for (int k0 = 0; k0 < K_; k0 += 64){
    #pragma unroll
    for (int q = 0; q < 4; q++){
      int r  = wave * 32 + q * 8 + srow;
      int ch = schunk ^ (r & 7);
      async16(A  + (size_t)(row0 + r) * K_ + k0 + ch * 8, As + (size_t)(wave*32 + q*8) * 128);
      async16(Bt + (size_t)(col0 + r) * K_ + k0 + ch * 8, Bs + (size_t)(wave*32 + q*8) * 128);
    }
    __syncthreads();

    #pragma unroll
    for (int s = 0; s < 2; s++){
      s16x8 af[4], bfr[4];
      #pragma unroll
      for (int i = 0; i < 4; i++){
        int row = wr + i*16 + lr;
        af[i] = *(const s16x8*)(As + row*128 + ((s*64 + lg*16) ^ ((row & 7) << 4)));
      }
      #pragma unroll
      for (int j = 0; j < 4; j++){
        int row = wc + j*16 + lr;
        bfr[j] = *(const s16x8*)(Bs + row*128 + ((s*64 + lg*16) ^ ((row & 7) << 4)));
      }
      #pragma unroll
      for (int i = 0; i < 4; i++)
        #pragma unroll
        for (int j = 0; j < 4; j++)
          acc[i][j] = __builtin_amdgcn_mfma_f32_16x16x32_bf16(af[i], bfr[j], acc[i][j], 0, 0, 0);
    }
    __syncthreads();
  }

  #pragma unroll
  for (int i = 0; i < 4; i++)
    #pragma unroll
    for (int j = 0; j < 4; j++){
      int col = col0 + wc + j*16 + lr;
      float bc = bias[col];
      #pragma unroll
      for (int r = 0; r < 4; r++){
        int row = row0 + wr + i*16 + lg*4 + r;
        size_t idx = (size_t)row * N_ + col;
        float v = acc[i][j][r] + bc;
        if (EPI == 1) DstB[idx] = f2bf(gelu_exact(v));
        else          DstF[idx] += v;
      }
    }
}

extern "C" void kernel_launch(void* const* d_in, const int* in_sizes, int n_in,
                              void* d_out, int out_size, void* d_ws, size_t ws_size,
                              hipStream_t stream)
{
  const float* x      = (const float*)d_in[0];
  const float* ctx    = (const float*)d_in[1];
  const float* ln1w   = (const float*)d_in[2];
  const float* ln1b   = (const float*)d_in[3];
  const float* w_qkv  = (const float*)d_in[4];
  const float* b_qkv  = (const float*)d_in[5];
  const float* w_fc_s = (const float*)d_in[6];
  const float* b_fc_s = (const float*)d_in[7];
  const float* ln2w   = (const float*)d_in[8];
  const float* ln2b   = (const float*)d_in[9];
  const float* w_q    = (const float*)d_in[10];
  const float* b_q    = (const float*)d_in[11];
  const float* w_kv   = (const float*)d_in[12];
  const float* b_kv   = (const float*)d_in[13];
  const float* w_fc_c = (const float*)d_in[14];
  const float* b_fc_c = (const float*)d_in[15];
  const float* ln3w   = (const float*)d_in[16];
  const float* ln3b   = (const float*)d_in[17];
  const float* w1     = (const float*)d_in[18];
  const float* b1     = (const float*)d_in[19];
  const float* w2     = (const float*)d_in[20];
  const float* b2     = (const float*)d_in[21];

  float* out = (float*)d_out;
  char* wsb = (char*)d_ws;
  __hip_bfloat16* Y   = (__hip_bfloat16*)wsb;                                  // 16 MB
  __hip_bfloat16* mid = (__hip_bfloat16*)(wsb + (size_t)TOKENS*HD*2);          // 64 MB
  __hip_bfloat16* w1t = (__hip_bfloat16*)(wsb + (size_t)TOKENS*HD*2 + (size_t)TOKENS*MM*2);
  __hip_bfloat16* w2t = (__hip_bfloat16*)(wsb + (size_t)TOKENS*HD*2 + (size_t)TOKENS*MM*2 + (size_t)HD*MM*2);

  // small pre-transposed weights live at the head of `mid`: stage_a reads them
  // strictly before gemm1 overwrites mid (stream-ordered, graph-replay safe).
  __hip_bfloat16* qkvT = mid;                 // [8][192][64]  98304 el
  __hip_bfloat16* qT   = mid + 98304;         // [8][64][64]   32768 el
  __hip_bfloat16* kvT  = mid + 131072;        // [8][128][64]  65536 el
  __hip_bfloat16* fcsT = mid + 196608;        // [64][64]       4096 el
  __hip_bfloat16* fccT = mid + 200704;        // [64][64]       4096 el

  convT<<<dim3( 2,  6, 8), 256, 0, stream>>>(w_qkv,  qkvT, 64, 192);
  convT<<<dim3( 2,  2, 8), 256, 0, stream>>>(w_q,    qT,   64, 64);
  convT<<<dim3( 2,  4, 8), 256, 0, stream>>>(w_kv,   kvT,  64, 128);
  convT<<<dim3( 2,  2, 1), 256, 0, stream>>>(w_fc_s, fcsT, 64, 64);
  convT<<<dim3( 2,  2, 1), 256, 0, stream>>>(w_fc_c, fccT, 64, 64);
  convT<<<dim3(16, 64, 1), 256, 0, stream>>>(w1,     w1t,  HD, MM);   // -> [2048][512]
  convT<<<dim3(64, 16, 1), 256, 0, stream>>>(w2,     w2t,  MM, HD);   // -> [512][2048]

  fused_stage_a<<<TOKENS/TB, 256, 0, stream>>>(x, ctx, ln1w, ln1b, qkvT, b_qkv,
                                               fcsT, b_fc_s, ln2w, ln2b, qT, b_q,
                                               kvT, b_kv, fccT, b_fc_c, ln3w, ln3b,
                                               out, Y);

  gemm_bt<1><<<dim3(TOKENS/128, MM/128), 256, 0, stream>>>(Y,   w1t, b1, mid, nullptr, TOKENS, MM, HD);
  gemm_bt<2><<<dim3(TOKENS/128, HD/128), 256, 0, stream>>>(mid, w2t, b2, nullptr, out, TOKENS, HD, MM);
}